// Round 1
// baseline (69046.527 us; speedup 1.0000x reference)
//
#include <hip/hip_runtime.h>
#include <math.h>

// Echo-state network scan, persistent cooperative kernel.
// G=32 blocks (1 per CU guaranteed resident: 32 << 256 CUs), 256 threads each.
// Each block owns 32 rows of W (1024x1024 fp32) in REGISTERS (128 floats/thread).
// Per-step state exchange: self-validating 64-bit packets (tag<<32 | fp32 bits),
// relaxed agent-scope 8B atomic stores/loads -> single round-trip handshake.

#define G_BLOCKS 32
#define ROWS     32     // rows per block = 1024 / G_BLOCKS
#define TPB      256
#define T_STEPS  32768
#define R_DIM    1024
#define IN_DIM   128
#define OUT_DIM  64

__global__ __launch_bounds__(TPB, 1)
void esn_scan_kernel(const float* __restrict__ x,     // [T][128]
                     const float* __restrict__ Win,   // [1024][128]
                     const float* __restrict__ W,     // [1024][1024]
                     const float* __restrict__ Wout,  // [1024][64]
                     float* __restrict__ out,         // [T][64], pre-zeroed
                     unsigned long long* __restrict__ sbuf) // ws: [2][1024] u64
{
    constexpr float A   = 0.5f;   // leak rate
    constexpr float DEC = 0.5f;   // 1 - leak rate

    const int b    = blockIdx.x;
    const int tid  = threadIdx.x;
    const int lane = tid & 63;
    const int wave = tid >> 6;
    const int r    = tid & 31;    // local row for matvec partial
    const int kg   = tid >> 5;    // k-group 0..7 (128 k-elems each)

    __shared__ float s_dec[R_DIM];          // (1-a)*s_{t-1}, full vector
    __shared__ float part[8][ROWS];         // matvec partials [kg][row]
    __shared__ float u_lds[2][ROWS];        // input projection, dbuf by parity
    __shared__ float s_new_lds[ROWS];       // this block's new state chunk
    __shared__ float x_lds[2][IN_DIM];      // prefetched inputs, dbuf by parity
    __shared__ float win_lds[ROWS * 132];   // Win chunk, padded row stride 132
    __shared__ float wout_lds[ROWS * OUT_DIM];

    // ---- one-time setup ----
    // W chunk -> registers: thread (r,kg) holds W[b*32+r][kg*128 .. +127]
    float w[128];
    {
        const float* wrow = W + ((size_t)(b * ROWS + r)) * R_DIM + kg * 128;
        #pragma unroll
        for (int j = 0; j < 128; j += 4) {
            const float4 v = *(const float4*)(wrow + j);
            w[j] = v.x; w[j+1] = v.y; w[j+2] = v.z; w[j+3] = v.w;
        }
    }
    for (int i = tid; i < ROWS * IN_DIM; i += TPB) {
        int rr = i >> 7, cc = i & 127;
        win_lds[rr * 132 + cc] = Win[((size_t)(b * ROWS + rr)) * IN_DIM + cc];
    }
    for (int i = tid; i < ROWS * OUT_DIM; i += TPB)
        wout_lds[i] = Wout[(size_t)b * ROWS * OUT_DIM + i];
    for (int i = tid; i < R_DIM; i += TPB) s_dec[i] = 0.0f;   // s_{-1} = 0
    if (tid < IN_DIM) {
        x_lds[0][tid] = x[tid];            // x_0
        x_lds[1][tid] = x[IN_DIM + tid];   // x_1
    }
    __syncthreads();

    // u_0 by wave 1
    if (wave == 1) {
        int rr = lane & 31, kh = lane >> 5;
        float acc = 0.f;
        const float* wl = &win_lds[rr * 132 + kh * 64];
        const float* xl = &x_lds[0][kh * 64];
        #pragma unroll
        for (int i = 0; i < 64; i += 4) {
            float4 wv = *(const float4*)(wl + i);
            float4 xv = *(const float4*)(xl + i);
            acc += wv.x*xv.x + wv.y*xv.y + wv.z*xv.z + wv.w*xv.w;
        }
        acc += __shfl_down(acc, 32);
        if (lane < 32) u_lds[0][rr] = acc;
    }
    __syncthreads();

    // ---- main scan ----
    for (int t = 0; t < T_STEPS; ++t) {
        // Phase A: matvec partials, all waves. part[kg][r] = W[r][kg-span] . s_dec
        {
            float a0 = 0.f, a1 = 0.f, a2 = 0.f, a3 = 0.f;
            const float* sp = &s_dec[kg * 128];
            #pragma unroll
            for (int j = 0; j < 128; j += 4) {
                const float4 sv = *(const float4*)(sp + j);
                a0 += w[j]   * sv.x;
                a1 += w[j+1] * sv.y;
                a2 += w[j+2] * sv.z;
                a3 += w[j+3] * sv.w;
            }
            part[kg][r] = (a0 + a1) + (a2 + a3);
        }
        __syncthreads();

        // Phase B
        if (wave == 0) {
            // reduce partials, finish the step, publish own chunk (critical path)
            float snew = 0.f;
            if (lane < 32) {
                float tot = 0.f;
                #pragma unroll
                for (int k = 0; k < 8; ++k) tot += part[k][lane];
                const float y  = u_lds[t & 1][lane] + tot;
                const float sd = s_dec[b * ROWS + lane];
                snew = sd + A * tanhf(y);
                s_new_lds[lane] = snew;
                const unsigned long long pkt =
                    ((unsigned long long)(unsigned int)(t + 1) << 32)
                    | (unsigned long long)__float_as_uint(snew);
                __hip_atomic_store(&sbuf[(size_t)(t & 1) * R_DIM + b * ROWS + lane],
                                   pkt, __ATOMIC_RELAXED, __HIP_MEMORY_SCOPE_AGENT);
            }
        } else if (wave == 1 && t + 1 < T_STEPS) {
            // prefetch x_{t+2} and compute u_{t+1} (off critical path)
            const int tpre = (t + 2 < T_STEPS) ? (t + 2) : (T_STEPS - 1);
            const float xv0 = x[(size_t)tpre * IN_DIM + lane];
            const float xv1 = x[(size_t)tpre * IN_DIM + 64 + lane];
            int rr = lane & 31, kh = lane >> 5;
            float acc = 0.f;
            const float* wl = &win_lds[rr * 132 + kh * 64];
            const float* xl = &x_lds[(t + 1) & 1][kh * 64];
            #pragma unroll
            for (int i = 0; i < 64; i += 4) {
                float4 wv = *(const float4*)(wl + i);
                float4 xv = *(const float4*)(xl + i);
                acc += wv.x*xv.x + wv.y*xv.y + wv.z*xv.z + wv.w*xv.w;
            }
            acc += __shfl_down(acc, 32);
            if (lane < 32) u_lds[(t + 1) & 1][rr] = acc;
            x_lds[t & 1][lane]      = xv0;
            x_lds[t & 1][64 + lane] = xv1;
        }
        __syncthreads();

        // Phase C: wave 2 does the output projection for step t (hidden under
        // the poll); all threads then poll-stage s_t for the next iteration.
        if (wave == 2) {
            float acc = 0.f;
            #pragma unroll
            for (int rr = 0; rr < 32; ++rr)
                acc += s_new_lds[rr] * wout_lds[rr * OUT_DIM + lane];
            atomicAdd(&out[(size_t)t * OUT_DIM + lane], acc);
        }
        if (t + 1 < T_STEPS) {
            const int want = t + 1;
            unsigned long long v[4];
            const size_t base = (size_t)(t & 1) * R_DIM;
            #pragma unroll
            for (int j = 0; j < 4; ++j)
                v[j] = __hip_atomic_load(&sbuf[base + j * TPB + tid],
                                         __ATOMIC_RELAXED, __HIP_MEMORY_SCOPE_AGENT);
            bool ok;
            do {
                ok = true;
                #pragma unroll
                for (int j = 0; j < 4; ++j) {
                    if ((int)(v[j] >> 32) != want) {
                        ok = false;
                        __builtin_amdgcn_s_sleep(1);
                        v[j] = __hip_atomic_load(&sbuf[base + j * TPB + tid],
                                                 __ATOMIC_RELAXED,
                                                 __HIP_MEMORY_SCOPE_AGENT);
                    }
                }
            } while (!ok);
            #pragma unroll
            for (int j = 0; j < 4; ++j)
                s_dec[j * TPB + tid] = __uint_as_float((unsigned int)v[j]) * DEC;
        }
        __syncthreads();
    }
}

extern "C" void kernel_launch(void* const* d_in, const int* in_sizes, int n_in,
                              void* d_out, int out_size, void* d_ws, size_t ws_size,
                              hipStream_t stream) {
    const float* x    = (const float*)d_in[0];   // input_data  [32768][128]
    const float* Win  = (const float*)d_in[1];   // input_weights [1024][128]
    const float* W    = (const float*)d_in[2];   // reservoir_weights [1024][1024]
    const float* Wout = (const float*)d_in[3];   // output_weights [1024][64]
    float* out = (float*)d_out;                  // [32768][64]
    unsigned long long* sbuf = (unsigned long long*)d_ws;  // 16 KB used

    // predictions accumulate via atomicAdd -> zero first (capture-safe)
    hipMemsetAsync(d_out, 0, (size_t)out_size * sizeof(float), stream);

    esn_scan_kernel<<<G_BLOCKS, TPB, 0, stream>>>(x, Win, W, Wout, out, sbuf);
}